// Round 18
// baseline (156.866 us; speedup 1.0000x reference)
//
#include <hip/hip_runtime.h>
#include <hip/hip_bf16.h>
#include <hip/hip_fp16.h>

#define NN 50000
#define NE 800000
#define HID 128
#define NG 256
#define NC 10
#define NB 196    // buckets of 256 dst nodes
#define CHUNK 4096
#define BCAP 8192 // fixed pairbuf capacity per bucket (mean 4096, sigma 64)
#define SCB 196   // (NE + CHUNK - 1) / CHUNK
#define MGB 782   // (NN + 63) / 64
#define WPB 32    // wpack blocks

using half8  = __attribute__((ext_vector_type(8))) _Float16;
using half2v = __attribute__((ext_vector_type(2))) _Float16;
using f32x4  = __attribute__((ext_vector_type(4))) float;

__device__ __forceinline__ float fdot2f(unsigned a, unsigned b, float c)
{
#if __has_builtin(__builtin_amdgcn_fdot2)
    return __builtin_amdgcn_fdot2(*(half2v*)&a, *(half2v*)&b, c, false);
#else
    float2 fa = __half22float2(*(__half2*)&a);
    float2 fb = __half22float2(*(__half2*)&b);
    return fmaf(fa.x, fb.x, fmaf(fa.y, fb.y, c));
#endif
}

// packed leaky_relu(xl + xr) in fp16: max(s, 0.2*s)
__device__ __forceinline__ unsigned addleaky_h2(unsigned xl, unsigned xr)
{
    half2v s = *(half2v*)&xl + *(half2v*)&xr;
    half2v l = __builtin_elementwise_max(s, s * (_Float16)0.2f);
    return *(unsigned*)&l;
}

// ---------------------------------------------------------------------------
// W pack body: both layers, 32 blocks x 256 threads (gidx 0..8191).
// ---------------------------------------------------------------------------
__device__ __forceinline__ void wpack_body(
    int blk, const float* __restrict__ Wl1, const float* __restrict__ Wr1,
    const float* __restrict__ Wl2, const float* __restrict__ Wr2,
    __half* __restrict__ wpk1, __half* __restrict__ wpk2)
{
    int gidx = blk * 256 + threadIdx.x;    // 0..8191
    int idx = gidx & 4095;
    int layer = gidx >> 12;
    const float* Wl = layer ? Wl2 : Wl1;
    const float* Wr = layer ? Wr2 : Wr1;
    __half* wpk = layer ? wpk2 : wpk1;

    int t = idx >> 8;
    int lane = idx & 63;
    const float* W = (t < 8) ? Wl : Wr;
    int col = ((t & 7) << 4) + (lane & 15);
    int k0 = (((idx >> 6) & 3) << 5) + ((lane >> 4) << 3);
    __half tmp[8];
#pragma unroll
    for (int j = 0; j < 8; j++)
        tmp[j] = __float2half(W[(size_t)(k0 + j) * 128 + col]);
    *(uint4*)(wpk + ((size_t)idx << 3)) = *(uint4*)tmp;
}

// ---------------------------------------------------------------------------
// MFMA dual GEMM body: xlh = fp16(in @ Wl), xrh = fp16(in @ Wr).
// ---------------------------------------------------------------------------
template <bool F32IN>
__device__ __forceinline__ void mgemm_body(
    int blk, const void* __restrict__ in, const __half* __restrict__ wpk,
    __half* __restrict__ xlh, __half* __restrict__ xrh)
{
    const int w = threadIdx.x >> 6;
    const int lane = threadIdx.x & 63;
    const int nodebase = blk * 64 + w * 16;
    const int lrow = lane & 15;
    const int kb = lane >> 4;

    const int nload = min(nodebase + lrow, NN - 1);

    half8 a[4];
    if constexpr (F32IN) {
        const float* xp = (const float*)in + (size_t)nload * 128 + (kb << 3);
#pragma unroll
        for (int kf = 0; kf < 4; kf++) {
            float4 f0 = *(const float4*)(xp + kf * 32);
            float4 f1 = *(const float4*)(xp + kf * 32 + 4);
            half8 hh;
            hh[0] = (_Float16)f0.x; hh[1] = (_Float16)f0.y;
            hh[2] = (_Float16)f0.z; hh[3] = (_Float16)f0.w;
            hh[4] = (_Float16)f1.x; hh[5] = (_Float16)f1.y;
            hh[6] = (_Float16)f1.z; hh[7] = (_Float16)f1.w;
            a[kf] = hh;
        }
    } else {
        const char* xp = (const char*)in + (size_t)nload * 256 + (kb << 4);
#pragma unroll
        for (int kf = 0; kf < 4; kf++) {
            uint4 u = *(const uint4*)(xp + kf * 64);
            a[kf] = *(half8*)&u;
        }
    }

    const uint4* wp = (const uint4*)wpk + lane;

#pragma unroll
    for (int t = 0; t < 16; t++) {
        f32x4 acc = {0.f, 0.f, 0.f, 0.f};
#pragma unroll
        for (int kf = 0; kf < 4; kf++) {
            uint4 bu = wp[(t * 4 + kf) * 64];
            half8 b = *(half8*)&bu;
            acc = __builtin_amdgcn_mfma_f32_16x16x32_f16(a[kf], b, acc, 0, 0, 0);
        }
        int col = ((t & 7) << 4) + lrow;
#pragma unroll
        for (int i = 0; i < 4; i++) {
            int node = nodebase + kb * 4 + i;
            if (node < NN) {
                if (t < 8) xlh[(size_t)node * 128 + col] = __float2half(acc[i]);
                else       xrh[(size_t)node * 128 + col] = __float2half(acc[i]);
            }
        }
    }
}

// ---------------------------------------------------------------------------
// Bucketed CSR scatter body. pairbuf slot b*BCAP; counts via cursor atomics.
// pair = (src << 8) | (dst & 255)
// ---------------------------------------------------------------------------
__device__ __forceinline__ int block_scan_incl(int v, int t)
{
    __shared__ int sm[256];
    sm[t] = v;
    __syncthreads();
#pragma unroll
    for (int off = 1; off < 256; off <<= 1) {
        int u = (t >= off) ? sm[t - off] : 0;
        __syncthreads();
        sm[t] += u;
        __syncthreads();
    }
    return sm[t];
}

__device__ __forceinline__ void bscatter_body(
    int blk, const int* __restrict__ ei, int* __restrict__ cursor,
    unsigned* __restrict__ pairbuf)
{
    __shared__ int lcnt[256], cstart[256], lcur[256], gpos[256];
    __shared__ unsigned sorted[CHUNK];
    __shared__ unsigned char sortedB[CHUNK];
    const int t = threadIdx.x;
    const int base = blk * CHUNK;
    const int n = min(CHUNK, NE - base);
    if (n <= 0) return;

    lcnt[t] = 0;
    __syncthreads();

    unsigned pk[16];
    int bk[16];
#pragma unroll
    for (int i = 0; i < 16; i++) {
        int off = i * 256 + t;
        bk[i] = -1;
        if (off < n) {
            int e = base + off;
            int s = ei[e], d = ei[NE + e];
            bk[i] = d >> 8;
            pk[i] = ((unsigned)s << 8) | (unsigned)(d & 255);
            atomicAdd(&lcnt[bk[i]], 1);
        }
    }
    __syncthreads();

    int v = lcnt[t];
    int inc = block_scan_incl(v, t);
    cstart[t] = inc - v;
    lcur[t] = inc - v;
    __syncthreads();
    gpos[t] = (v > 0) ? atomicAdd(&cursor[t], v) : 0;
    __syncthreads();

#pragma unroll
    for (int i = 0; i < 16; i++) {
        if (bk[i] >= 0) {
            int r = atomicAdd(&lcur[bk[i]], 1);
            sorted[r] = pk[i];
            sortedB[r] = (unsigned char)bk[i];
        }
    }
    __syncthreads();

    for (int j = t; j < n; j += 256) {
        int b = sortedB[j];
        pairbuf[(size_t)b * BCAP + gpos[b] + (j - cstart[b])] = sorted[j];
    }
}

// per-bucket: redundant 196-scan for row base; rowptr + self-loop + esrc.
__device__ __forceinline__ void bbuild_body(
    int b, const unsigned* __restrict__ pairbuf, const int* __restrict__ cursor,
    int* __restrict__ rowptr, int* __restrict__ esrc)
{
    __shared__ int pre[256];
    __shared__ int ncnt[256], cur[256];
    const int t = threadIdx.x;
    const int node0 = b * 256;
    const int nnodes = min(256, NN - node0);

    int cb = (t < NB) ? cursor[t] : 0;
    int nodes = (t < NB) ? min(256, NN - t * 256) : 0;
    int inc = block_scan_incl(cb + nodes, t);
    pre[t] = inc;
    __syncthreads();
    const int row0 = (b == 0) ? 0 : pre[b - 1];
    const int cnt = cursor[b];
    const unsigned* pb = pairbuf + (size_t)b * BCAP;

    ncnt[t] = 0;
    __syncthreads();
    for (int i = t; i < cnt; i += 256)
        atomicAdd(&ncnt[pb[i] & 255u], 1);
    __syncthreads();

    int v = (t < nnodes) ? ncnt[t] + 1 : 0;  // +1 self-loop
    int inc2 = block_scan_incl(v, t);
    int rb = row0 + inc2 - v;
    if (t < nnodes) {
        rowptr[node0 + t] = rb;
        esrc[rb] = node0 + t;
        cur[t] = rb + 1;
    }
    if (b == NB - 1 && t == 0) rowptr[NN] = NE + NN;
    __syncthreads();

    for (int i = t; i < cnt; i += 256) {
        unsigned p = pb[i];
        int pos = atomicAdd(&cur[p & 255u], 1);
        esrc[pos] = (int)(p >> 8);
    }
}

// merged kernel 1: [0,WPB) W pack, [WPB, WPB+SCB) bucket scatter
__global__ __launch_bounds__(256) void k_wpsc(
    const float* __restrict__ Wl1, const float* __restrict__ Wr1,
    const float* __restrict__ Wl2, const float* __restrict__ Wr2,
    __half* __restrict__ wpk1, __half* __restrict__ wpk2,
    const int* __restrict__ ei, int* __restrict__ cursor,
    unsigned* __restrict__ pairbuf)
{
    if (blockIdx.x < WPB)
        wpack_body(blockIdx.x, Wl1, Wr1, Wl2, Wr2, wpk1, wpk2);
    else
        bscatter_body(blockIdx.x - WPB, ei, cursor, pairbuf);
}

// merged kernel 2: [0,NB) CSR finalize, [NB, NB+MGB) layer-1 MFMA GEMM
__global__ __launch_bounds__(256) void k_bdmg(
    const unsigned* __restrict__ pairbuf, const int* __restrict__ cursor,
    int* __restrict__ rowptr, int* __restrict__ esrc,
    const float* __restrict__ x, const __half* __restrict__ wpk1,
    __half* __restrict__ xlh, __half* __restrict__ xrh)
{
    if (blockIdx.x < NB)
        bbuild_body(blockIdx.x, pairbuf, cursor, rowptr, esrc);
    else
        mgemm_body<true>(blockIdx.x - NB, x, wpk1, xlh, xrh);
}

__global__ __launch_bounds__(256) void k_mgemm2(
    const __half* __restrict__ in, const __half* __restrict__ wpk,
    __half* __restrict__ xlh, __half* __restrict__ xrh)
{
    mgemm_body<false>(blockIdx.x, in, wpk, xlh, xrh);
}

// ---------------------------------------------------------------------------
// GAT core: wave per dst node; four 16-lane groups, 4 edges/step.
// ---------------------------------------------------------------------------
#define GAT_LOGIT(A, e)                                                     \
    {                                                                       \
        unsigned l0 = addleaky_h2(A.x, xrq.x);                              \
        unsigned l1 = addleaky_h2(A.y, xrq.y);                              \
        unsigned l2 = addleaky_h2(A.z, xrq.z);                              \
        unsigned l3 = addleaky_h2(A.w, xrq.w);                              \
        e = fdot2f(l0, atq.x, 0.f);                                         \
        e = fdot2f(l1, atq.y, e);                                           \
        e = fdot2f(l2, atq.z, e);                                           \
        e = fdot2f(l3, atq.w, e);                                           \
        _Pragma("unroll")                                                   \
        for (int off = 8; off; off >>= 1) e += __shfl_xor(e, off, 64);      \
    }

#define GAT_ACC(A, p)                                                       \
    {                                                                       \
        half8 ah = *(half8*)&A;                                             \
        _Pragma("unroll")                                                   \
        for (int i = 0; i < 8; i++)                                         \
            acc[i] = fmaf(p, (float)ah[i], acc[i]);                         \
    }

__device__ __forceinline__ void gat_core(
    const char* __restrict__ xlb, const int* __restrict__ esrc,
    int beg, int end, int lane, const uint4 xrq, const uint4 atq,
    float* acc, float& den)
{
    const int g = lane >> 4;
    const unsigned qb = (unsigned)((lane & 15) << 4);
#pragma unroll
    for (int i = 0; i < 8; i++) acc[i] = 0.f;
    den = 0.f;

    for (int sc = beg; sc < end; sc += 64) {
        const int nv = min(end - sc, 64);
        const int nit = (nv + 3) >> 2;
        const int nfull = nv >> 2;
        int myidx = esrc[sc + lane] & 0xFFFF;   // bounded (garbage lanes safe)

        auto LD = [&](int j) -> uint4 {
            int t = (j << 2) + g;
            int s = __shfl(myidx, t, 64);
            unsigned off = ((unsigned)s << 8) | qb;
            return *(const uint4*)(xlb + off);
        };

        uint4 A = LD(0);
        uint4 B = LD(1 < nit ? 1 : 0);

#pragma unroll 2
        for (int jj = 0; jj < nfull; ++jj) {
            uint4 C = LD(jj + 2 < nit ? jj + 2 : nit - 1);
            float e;
            GAT_LOGIT(A, e)
            float p = __expf(fminf(e, 80.f));
            den += p;
            GAT_ACC(A, p)
            A = B; B = C;
        }
        if (nv & 3) {   // tail
            float e;
            GAT_LOGIT(A, e)
            float p = ((nfull << 2) + g < nv) ? __expf(fminf(e, 80.f)) : 0.f;
            den += p;
            GAT_ACC(A, p)
        }
    }

#pragma unroll
    for (int off = 16; off < 64; off <<= 1) {
        den += __shfl_xor(den, off, 64);
#pragma unroll
        for (int i = 0; i < 8; i++) acc[i] += __shfl_xor(acc[i], off, 64);
    }
}

__device__ __forceinline__ uint4 ld_att_h2(const float* att, int q)
{
    float4 c = *(const float4*)(att + q * 8);
    float4 e = *(const float4*)(att + q * 8 + 4);
    __half2 t0 = __floats2half2_rn(c.x, c.y);
    __half2 t1 = __floats2half2_rn(c.z, c.w);
    __half2 t2 = __floats2half2_rn(e.x, e.y);
    __half2 t3 = __floats2half2_rn(e.z, e.w);
    uint4 r;
    r.x = *(unsigned*)&t0; r.y = *(unsigned*)&t1;
    r.z = *(unsigned*)&t2; r.w = *(unsigned*)&t3;
    return r;
}

// layer1: fused normalize + bias + ReLU + LayerNorm -> h16 (fp16)
__global__ __launch_bounds__(256, 8) void k_gat1(
    const char* __restrict__ xlb, const char* __restrict__ xrb,
    const float* __restrict__ att, const int* __restrict__ rowptr,
    const int* __restrict__ esrc, const float* __restrict__ bias,
    const float* __restrict__ g_ln, const float* __restrict__ b_ln,
    char* __restrict__ h16b)
{
    int d = (int)((blockIdx.x * 256 + threadIdx.x) >> 6);  // grid exact
    int lane = threadIdx.x & 63;
    int q = lane & 15;

    uint4 xrq = *(const uint4*)(xrb + ((size_t)d << 8) + (q << 4));
    uint4 atq = ld_att_h2(att, q);

    float acc[8]; float den;
    gat_core(xlb, esrc, rowptr[d], rowptr[d + 1], lane, xrq, atq, acc, den);

    float inv = 1.f / (den + 1e-16f);
    float x[8];
    {
        float4 a = *(const float4*)(bias + q * 8);
        float4 b = *(const float4*)(bias + q * 8 + 4);
        float bb[8] = {a.x,a.y,a.z,a.w,b.x,b.y,b.z,b.w};
#pragma unroll
        for (int i = 0; i < 8; i++) x[i] = fmaxf(fmaf(acc[i], inv, bb[i]), 0.f);
    }

    float s1 = 0.f, s2 = 0.f;
#pragma unroll
    for (int i = 0; i < 8; i++) { s1 += x[i]; s2 += x[i] * x[i]; }
#pragma unroll
    for (int off = 8; off; off >>= 1) {
        s1 += __shfl_xor(s1, off, 64);
        s2 += __shfl_xor(s2, off, 64);
    }
    float mu = s1 * (1.f / 128.f);
    float var = s2 * (1.f / 128.f) - mu * mu;
    float rstd = rsqrtf(var + 1e-5f);

    if (lane < 16) {
        float4 ga = *(const float4*)(g_ln + q * 8);
        float4 gb = *(const float4*)(g_ln + q * 8 + 4);
        float4 ba = *(const float4*)(b_ln + q * 8);
        float4 bb = *(const float4*)(b_ln + q * 8 + 4);
        float o[8];
        o[0] = (x[0]-mu)*rstd*ga.x + ba.x;
        o[1] = (x[1]-mu)*rstd*ga.y + ba.y;
        o[2] = (x[2]-mu)*rstd*ga.z + ba.z;
        o[3] = (x[3]-mu)*rstd*ga.w + ba.w;
        o[4] = (x[4]-mu)*rstd*gb.x + bb.x;
        o[5] = (x[5]-mu)*rstd*gb.y + bb.y;
        o[6] = (x[6]-mu)*rstd*gb.z + bb.z;
        o[7] = (x[7]-mu)*rstd*gb.w + bb.w;
        __half2 p0 = __floats2half2_rn(o[0], o[1]);
        __half2 p1 = __floats2half2_rn(o[2], o[3]);
        __half2 p2 = __floats2half2_rn(o[4], o[5]);
        __half2 p3 = __floats2half2_rn(o[6], o[7]);
        uint4 u;
        u.x = *(unsigned*)&p0; u.y = *(unsigned*)&p1;
        u.z = *(unsigned*)&p2; u.w = *(unsigned*)&p3;
        *(uint4*)(h16b + ((size_t)d << 8) + (q << 4)) = u;
    }
}

// layer2: fused normalize + bias -> h2h (fp16)
__global__ __launch_bounds__(256, 8) void k_gat2(
    const char* __restrict__ xlb, const char* __restrict__ xrb,
    const float* __restrict__ att, const int* __restrict__ rowptr,
    const int* __restrict__ esrc, const float* __restrict__ bias,
    char* __restrict__ h2b)
{
    int d = (int)((blockIdx.x * 256 + threadIdx.x) >> 6);
    int lane = threadIdx.x & 63;
    int q = lane & 15;

    uint4 xrq = *(const uint4*)(xrb + ((size_t)d << 8) + (q << 4));
    uint4 atq = ld_att_h2(att, q);

    float acc[8]; float den;
    gat_core(xlb, esrc, rowptr[d], rowptr[d + 1], lane, xrq, atq, acc, den);

    float inv = 1.f / (den + 1e-16f);
    if (lane < 16) {
        float4 a = *(const float4*)(bias + q * 8);
        float4 b = *(const float4*)(bias + q * 8 + 4);
        float o[8];
        o[0] = fmaf(acc[0], inv, a.x);
        o[1] = fmaf(acc[1], inv, a.y);
        o[2] = fmaf(acc[2], inv, a.z);
        o[3] = fmaf(acc[3], inv, a.w);
        o[4] = fmaf(acc[4], inv, b.x);
        o[5] = fmaf(acc[5], inv, b.y);
        o[6] = fmaf(acc[6], inv, b.z);
        o[7] = fmaf(acc[7], inv, b.w);
        __half2 p0 = __floats2half2_rn(o[0], o[1]);
        __half2 p1 = __floats2half2_rn(o[2], o[3]);
        __half2 p2 = __floats2half2_rn(o[4], o[5]);
        __half2 p3 = __floats2half2_rn(o[6], o[7]);
        uint4 u;
        u.x = *(unsigned*)&p0; u.y = *(unsigned*)&p1;
        u.z = *(unsigned*)&p2; u.w = *(unsigned*)&p3;
        *(uint4*)(h2b + ((size_t)d << 8) + (q << 4)) = u;
    }
}

// ---------------------------------------------------------------------------
// fused mean-pool + linear head: one block per graph (batch is sorted).
// 8 independent row loads in flight per step (latency-chain /8).
// ---------------------------------------------------------------------------
__global__ __launch_bounds__(128) void k_poolin(
    const __half* __restrict__ h2h, const int* __restrict__ batch,
    const float* __restrict__ W, const float* __restrict__ b,
    float* __restrict__ out)
{
    const int g = blockIdx.x;
    const int f = threadIdx.x;

    // node range [lo, lo2) with batch[n] == g
    int lo = 0, hi = NN;
    while (lo < hi) { int m = (lo + hi) >> 1; if (batch[m] < g) lo = m + 1; else hi = m; }
    int lo2 = lo, hi2 = NN;
    while (lo2 < hi2) { int m = (lo2 + hi2) >> 1; if (batch[m] <= g) lo2 = m + 1; else hi2 = m; }

    float s = 0.f;
    const int last = lo2 - 1;
    for (int n = lo; n < lo2; n += 8) {
        float v[8];
#pragma unroll
        for (int j = 0; j < 8; j++) {
            int nn = min(n + j, last);                  // clamped: loads stay unconditional
            v[j] = __half2float(h2h[(size_t)nn * 128 + f]);
        }
#pragma unroll
        for (int j = 0; j < 8; j++)
            s += (n + j < lo2) ? v[j] : 0.f;
    }

    __shared__ float sm[128];
    sm[f] = s;
    __syncthreads();

    if (f < NC) {
        float invc = 1.f / fmaxf((float)(lo2 - lo), 1.f);
        float a = 0.f;
        for (int k = 0; k < HID; k++)
            a = fmaf(sm[k], W[(size_t)k * NC + f], a);
        out[(size_t)g * NC + f] = fmaf(a, invc, b[f]);
    }
}

// ---------------------------------------------------------------------------
extern "C" void kernel_launch(void* const* d_in, const int* in_sizes, int n_in,
                              void* d_out, int out_size, void* d_ws, size_t ws_size,
                              hipStream_t stream)
{
    const float* x     = (const float*)d_in[0];
    const int*   ei    = (const int*)d_in[1];
    const int*   batch = (const int*)d_in[2];
    const float* Wl1   = (const float*)d_in[3];
    const float* Wr1   = (const float*)d_in[4];
    const float* att1  = (const float*)d_in[5];
    const float* b1    = (const float*)d_in[6];
    const float* g_ln  = (const float*)d_in[7];
    const float* b_ln  = (const float*)d_in[8];
    const float* Wl2   = (const float*)d_in[9];
    const float* Wr2   = (const float*)d_in[10];
    const float* att2  = (const float*)d_in[11];
    const float* b2    = (const float*)d_in[12];
    const float* Wlin  = (const float*)d_in[13];
    const float* blin  = (const float*)d_in[14];
    float* out = (float*)d_out;

    char* ws = (char*)d_ws;
    __half* xlh16 = (__half*)ws;                          // 12.8 MB
    char*   xlb   = ws;
    __half* xrh16 = (__half*)(ws + (size_t)NN * 256);     // 12.8 MB
    char*   xrb   = (char*)xrh16;
    __half* h16   = xrh16 + (size_t)NN * 128;             // 12.8 MB
    __half* h2h   = h16 + (size_t)NN * 128;               // 12.8 MB
    char*   h2b   = (char*)h2h;
    int* rowptr   = (int*)(h2h + (size_t)NN * 128);       // NN+1
    int* esrc     = rowptr + NN + 1;                      // NE+NN
    unsigned* pairbuf = (unsigned*)(esrc + NE + NN);      // NB*BCAP = 6.4 MB
    int* cursor   = (int*)(pairbuf + (size_t)NB * BCAP);  // 256
    __half* wpk1  = (__half*)(cursor + 256);              // 64 KB
    __half* wpk2  = wpk1 + 32768;                         // 64 KB

    const int gat_blocks = (NN * 64) / 256;               // exact: 12500

    // 0) zero scatter cursor (1 KB)
    hipMemsetAsync(cursor, 0, 256 * sizeof(int), stream);

    // 1) W pack (blocks 0..31) + bucket scatter (blocks 32..227)
    k_wpsc<<<WPB + SCB, 256, 0, stream>>>(Wl1, Wr1, Wl2, Wr2, wpk1, wpk2,
                                          ei, cursor, pairbuf);

    // 2) CSR finalize (blocks 0..195) + layer-1 dual GEMM (blocks 196..977)
    k_bdmg<<<NB + MGB, 256, 0, stream>>>(pairbuf, cursor, rowptr, esrc,
                                         x, wpk1, xlh16, xrh16);

    // 3) layer-1 GAT (+ReLU+LN)
    k_gat1<<<gat_blocks, 256, 0, stream>>>(xlb, xrb, att1, rowptr, esrc,
                                           b1, g_ln, b_ln, (char*)h16);

    // 4) layer-2 dual GEMM
    k_mgemm2<<<MGB, 256, 0, stream>>>(h16, wpk2, xlh16, xrh16);

    // 5) layer-2 GAT
    k_gat2<<<gat_blocks, 256, 0, stream>>>(xlb, xrb, att2, rowptr, esrc,
                                           b2, h2b);

    // 6) fused mean-pool + linear head
    k_poolin<<<NG, 128, 0, stream>>>(h2h, batch, Wlin, blin, out);
}

// Round 19
// 154.601 us; speedup vs baseline: 1.0147x; 1.0147x over previous
//
#include <hip/hip_runtime.h>
#include <hip/hip_bf16.h>
#include <hip/hip_fp16.h>

#define NN 50000
#define NE 800000
#define HID 128
#define NG 256
#define NC 10
#define NB 196    // buckets of 256 dst nodes
#define CHUNK 4096
#define BCAP 8192 // fixed pairbuf capacity per bucket (mean 4096, sigma 64)
#define SCB 196   // (NE + CHUNK - 1) / CHUNK
#define MGB 782   // (NN + 63) / 64

using half8  = __attribute__((ext_vector_type(8))) _Float16;
using half2v = __attribute__((ext_vector_type(2))) _Float16;
using f32x4  = __attribute__((ext_vector_type(4))) float;

__device__ __forceinline__ float fdot2f(unsigned a, unsigned b, float c)
{
#if __has_builtin(__builtin_amdgcn_fdot2)
    return __builtin_amdgcn_fdot2(*(half2v*)&a, *(half2v*)&b, c, false);
#else
    float2 fa = __half22float2(*(__half2*)&a);
    float2 fb = __half22float2(*(__half2*)&b);
    return fmaf(fa.x, fb.x, fmaf(fa.y, fb.y, c));
#endif
}

// packed leaky_relu(xl + xr) in fp16: max(s, 0.2*s)
__device__ __forceinline__ unsigned addleaky_h2(unsigned xl, unsigned xr)
{
    half2v s = *(half2v*)&xl + *(half2v*)&xr;
    half2v l = __builtin_elementwise_max(s, s * (_Float16)0.2f);
    return *(unsigned*)&l;
}

// ---------------------------------------------------------------------------
// W pack (both layers) + zero cursor.  grid = 32 x 256.
// ---------------------------------------------------------------------------
__global__ __launch_bounds__(256) void k_wpackz(
    const float* __restrict__ Wl1, const float* __restrict__ Wr1,
    const float* __restrict__ Wl2, const float* __restrict__ Wr2,
    __half* __restrict__ wpk1, __half* __restrict__ wpk2,
    int* __restrict__ cursor)
{
    int gidx = blockIdx.x * 256 + threadIdx.x;    // 0..8191
    if (gidx < 256) cursor[gidx] = 0;

    int idx = gidx & 4095;
    int layer = gidx >> 12;
    const float* Wl = layer ? Wl2 : Wl1;
    const float* Wr = layer ? Wr2 : Wr1;
    __half* wpk = layer ? wpk2 : wpk1;

    int t = idx >> 8;
    int lane = idx & 63;
    const float* W = (t < 8) ? Wl : Wr;
    int col = ((t & 7) << 4) + (lane & 15);
    int k0 = (((idx >> 6) & 3) << 5) + ((lane >> 4) << 3);
    __half tmp[8];
#pragma unroll
    for (int j = 0; j < 8; j++)
        tmp[j] = __float2half(W[(size_t)(k0 + j) * 128 + col]);
    *(uint4*)(wpk + ((size_t)idx << 3)) = *(uint4*)tmp;
}

// ---------------------------------------------------------------------------
// MFMA dual GEMM body: xlh = fp16(in @ Wl), xrh = fp16(in @ Wr).
// ---------------------------------------------------------------------------
template <bool F32IN>
__device__ __forceinline__ void mgemm_body(
    int blk, const void* __restrict__ in, const __half* __restrict__ wpk,
    __half* __restrict__ xlh, __half* __restrict__ xrh)
{
    const int w = threadIdx.x >> 6;
    const int lane = threadIdx.x & 63;
    const int nodebase = blk * 64 + w * 16;
    const int lrow = lane & 15;
    const int kb = lane >> 4;

    const int nload = min(nodebase + lrow, NN - 1);

    half8 a[4];
    if constexpr (F32IN) {
        const float* xp = (const float*)in + (size_t)nload * 128 + (kb << 3);
#pragma unroll
        for (int kf = 0; kf < 4; kf++) {
            float4 f0 = *(const float4*)(xp + kf * 32);
            float4 f1 = *(const float4*)(xp + kf * 32 + 4);
            half8 hh;
            hh[0] = (_Float16)f0.x; hh[1] = (_Float16)f0.y;
            hh[2] = (_Float16)f0.z; hh[3] = (_Float16)f0.w;
            hh[4] = (_Float16)f1.x; hh[5] = (_Float16)f1.y;
            hh[6] = (_Float16)f1.z; hh[7] = (_Float16)f1.w;
            a[kf] = hh;
        }
    } else {
        const char* xp = (const char*)in + (size_t)nload * 256 + (kb << 4);
#pragma unroll
        for (int kf = 0; kf < 4; kf++) {
            uint4 u = *(const uint4*)(xp + kf * 64);
            a[kf] = *(half8*)&u;
        }
    }

    const uint4* wp = (const uint4*)wpk + lane;

#pragma unroll
    for (int t = 0; t < 16; t++) {
        f32x4 acc = {0.f, 0.f, 0.f, 0.f};
#pragma unroll
        for (int kf = 0; kf < 4; kf++) {
            uint4 bu = wp[(t * 4 + kf) * 64];
            half8 b = *(half8*)&bu;
            acc = __builtin_amdgcn_mfma_f32_16x16x32_f16(a[kf], b, acc, 0, 0, 0);
        }
        int col = ((t & 7) << 4) + lrow;
#pragma unroll
        for (int i = 0; i < 4; i++) {
            int node = nodebase + kb * 4 + i;
            if (node < NN) {
                if (t < 8) xlh[(size_t)node * 128 + col] = __float2half(acc[i]);
                else       xrh[(size_t)node * 128 + col] = __float2half(acc[i]);
            }
        }
    }
}

// ---------------------------------------------------------------------------
// Bucketed CSR scatter body. pairbuf slot b*BCAP; counts via cursor atomics.
// pair = (src << 8) | (dst & 255)
// ---------------------------------------------------------------------------
__device__ __forceinline__ int block_scan_incl(int v, int t)
{
    __shared__ int sm[256];
    sm[t] = v;
    __syncthreads();
#pragma unroll
    for (int off = 1; off < 256; off <<= 1) {
        int u = (t >= off) ? sm[t - off] : 0;
        __syncthreads();
        sm[t] += u;
        __syncthreads();
    }
    return sm[t];
}

__device__ __forceinline__ void bscatter_body(
    int blk, const int* __restrict__ ei, int* __restrict__ cursor,
    unsigned* __restrict__ pairbuf)
{
    __shared__ int lcnt[256], cstart[256], lcur[256], gpos[256];
    __shared__ unsigned sorted[CHUNK];
    __shared__ unsigned char sortedB[CHUNK];
    const int t = threadIdx.x;
    const int base = blk * CHUNK;
    const int n = min(CHUNK, NE - base);
    if (n <= 0) return;

    lcnt[t] = 0;
    __syncthreads();

    unsigned pk[16];
    int bk[16];
#pragma unroll
    for (int i = 0; i < 16; i++) {
        int off = i * 256 + t;
        bk[i] = -1;
        if (off < n) {
            int e = base + off;
            int s = ei[e], d = ei[NE + e];
            bk[i] = d >> 8;
            pk[i] = ((unsigned)s << 8) | (unsigned)(d & 255);
            atomicAdd(&lcnt[bk[i]], 1);
        }
    }
    __syncthreads();

    int v = lcnt[t];
    int inc = block_scan_incl(v, t);
    cstart[t] = inc - v;
    lcur[t] = inc - v;
    __syncthreads();
    gpos[t] = (v > 0) ? atomicAdd(&cursor[t], v) : 0;
    __syncthreads();

#pragma unroll
    for (int i = 0; i < 16; i++) {
        if (bk[i] >= 0) {
            int r = atomicAdd(&lcur[bk[i]], 1);
            sorted[r] = pk[i];
            sortedB[r] = (unsigned char)bk[i];
        }
    }
    __syncthreads();

    for (int j = t; j < n; j += 256) {
        int b = sortedB[j];
        pairbuf[(size_t)b * BCAP + gpos[b] + (j - cstart[b])] = sorted[j];
    }
}

// merged: blocks [0,SCB) scatter, [SCB, SCB+MGB) layer-1 MFMA GEMM
__global__ __launch_bounds__(256) void k_bscmg(
    const int* __restrict__ ei, int* __restrict__ cursor,
    unsigned* __restrict__ pairbuf, const float* __restrict__ x,
    const __half* __restrict__ wpk1, __half* __restrict__ xlh,
    __half* __restrict__ xrh)
{
    if (blockIdx.x < SCB)
        bscatter_body(blockIdx.x, ei, cursor, pairbuf);
    else
        mgemm_body<true>(blockIdx.x - SCB, x, wpk1, xlh, xrh);
}

__global__ __launch_bounds__(256) void k_mgemm2(
    const __half* __restrict__ in, const __half* __restrict__ wpk,
    __half* __restrict__ xlh, __half* __restrict__ xrh)
{
    mgemm_body<false>(blockIdx.x, in, wpk, xlh, xrh);
}

// per-bucket: redundant 196-scan for row base; rowptr + self-loop + esrc.
__global__ __launch_bounds__(256) void k_bbuild(
    const unsigned* __restrict__ pairbuf, const int* __restrict__ cursor,
    int* __restrict__ rowptr, int* __restrict__ esrc)
{
    __shared__ int pre[256];
    __shared__ int ncnt[256], cur[256];
    const int b = blockIdx.x;
    const int t = threadIdx.x;
    const int node0 = b * 256;
    const int nnodes = min(256, NN - node0);

    int cb = (t < NB) ? cursor[t] : 0;
    int nodes = (t < NB) ? min(256, NN - t * 256) : 0;
    int inc = block_scan_incl(cb + nodes, t);
    pre[t] = inc;
    __syncthreads();
    const int row0 = (b == 0) ? 0 : pre[b - 1];
    const int cnt = cursor[b];
    const unsigned* pb = pairbuf + (size_t)b * BCAP;

    ncnt[t] = 0;
    __syncthreads();
    for (int i = t; i < cnt; i += 256)
        atomicAdd(&ncnt[pb[i] & 255u], 1);
    __syncthreads();

    int v = (t < nnodes) ? ncnt[t] + 1 : 0;  // +1 self-loop
    int inc2 = block_scan_incl(v, t);
    int rb = row0 + inc2 - v;
    if (t < nnodes) {
        rowptr[node0 + t] = rb;
        esrc[rb] = node0 + t;
        cur[t] = rb + 1;
    }
    if (b == NB - 1 && t == 0) rowptr[NN] = NE + NN;
    __syncthreads();

    for (int i = t; i < cnt; i += 256) {
        unsigned p = pb[i];
        int pos = atomicAdd(&cur[p & 255u], 1);
        esrc[pos] = (int)(p >> 8);
    }
}

// ---------------------------------------------------------------------------
// GAT core: wave per dst node; four 16-lane groups, 4 edges/step.
// ---------------------------------------------------------------------------
#define GAT_LOGIT(A, e)                                                     \
    {                                                                       \
        unsigned l0 = addleaky_h2(A.x, xrq.x);                              \
        unsigned l1 = addleaky_h2(A.y, xrq.y);                              \
        unsigned l2 = addleaky_h2(A.z, xrq.z);                              \
        unsigned l3 = addleaky_h2(A.w, xrq.w);                              \
        e = fdot2f(l0, atq.x, 0.f);                                         \
        e = fdot2f(l1, atq.y, e);                                           \
        e = fdot2f(l2, atq.z, e);                                           \
        e = fdot2f(l3, atq.w, e);                                           \
        _Pragma("unroll")                                                   \
        for (int off = 8; off; off >>= 1) e += __shfl_xor(e, off, 64);      \
    }

#define GAT_ACC(A, p)                                                       \
    {                                                                       \
        half8 ah = *(half8*)&A;                                             \
        _Pragma("unroll")                                                   \
        for (int i = 0; i < 8; i++)                                         \
            acc[i] = fmaf(p, (float)ah[i], acc[i]);                         \
    }

__device__ __forceinline__ void gat_core(
    const char* __restrict__ xlb, const int* __restrict__ esrc,
    int beg, int end, int lane, const uint4 xrq, const uint4 atq,
    float* acc, float& den)
{
    const int g = lane >> 4;
    const unsigned qb = (unsigned)((lane & 15) << 4);
#pragma unroll
    for (int i = 0; i < 8; i++) acc[i] = 0.f;
    den = 0.f;

    for (int sc = beg; sc < end; sc += 64) {
        const int nv = min(end - sc, 64);
        const int nit = (nv + 3) >> 2;
        const int nfull = nv >> 2;
        int myidx = esrc[sc + lane] & 0xFFFF;   // bounded (garbage lanes safe)

        auto LD = [&](int j) -> uint4 {
            int t = (j << 2) + g;
            int s = __shfl(myidx, t, 64);
            unsigned off = ((unsigned)s << 8) | qb;
            return *(const uint4*)(xlb + off);
        };

        uint4 A = LD(0);
        uint4 B = LD(1 < nit ? 1 : 0);

#pragma unroll 2
        for (int jj = 0; jj < nfull; ++jj) {
            uint4 C = LD(jj + 2 < nit ? jj + 2 : nit - 1);
            float e;
            GAT_LOGIT(A, e)
            float p = __expf(fminf(e, 80.f));
            den += p;
            GAT_ACC(A, p)
            A = B; B = C;
        }
        if (nv & 3) {   // tail
            float e;
            GAT_LOGIT(A, e)
            float p = ((nfull << 2) + g < nv) ? __expf(fminf(e, 80.f)) : 0.f;
            den += p;
            GAT_ACC(A, p)
        }
    }

#pragma unroll
    for (int off = 16; off < 64; off <<= 1) {
        den += __shfl_xor(den, off, 64);
#pragma unroll
        for (int i = 0; i < 8; i++) acc[i] += __shfl_xor(acc[i], off, 64);
    }
}

__device__ __forceinline__ uint4 ld_att_h2(const float* att, int q)
{
    float4 c = *(const float4*)(att + q * 8);
    float4 e = *(const float4*)(att + q * 8 + 4);
    __half2 t0 = __floats2half2_rn(c.x, c.y);
    __half2 t1 = __floats2half2_rn(c.z, c.w);
    __half2 t2 = __floats2half2_rn(e.x, e.y);
    __half2 t3 = __floats2half2_rn(e.z, e.w);
    uint4 r;
    r.x = *(unsigned*)&t0; r.y = *(unsigned*)&t1;
    r.z = *(unsigned*)&t2; r.w = *(unsigned*)&t3;
    return r;
}

// layer1: fused normalize + bias + ReLU + LayerNorm -> h16 (fp16)
__global__ __launch_bounds__(256, 8) void k_gat1(
    const char* __restrict__ xlb, const char* __restrict__ xrb,
    const float* __restrict__ att, const int* __restrict__ rowptr,
    const int* __restrict__ esrc, const float* __restrict__ bias,
    const float* __restrict__ g_ln, const float* __restrict__ b_ln,
    char* __restrict__ h16b)
{
    int d = (int)((blockIdx.x * 256 + threadIdx.x) >> 6);  // grid exact
    int lane = threadIdx.x & 63;
    int q = lane & 15;

    uint4 xrq = *(const uint4*)(xrb + ((size_t)d << 8) + (q << 4));
    uint4 atq = ld_att_h2(att, q);

    float acc[8]; float den;
    gat_core(xlb, esrc, rowptr[d], rowptr[d + 1], lane, xrq, atq, acc, den);

    float inv = 1.f / (den + 1e-16f);
    float x[8];
    {
        float4 a = *(const float4*)(bias + q * 8);
        float4 b = *(const float4*)(bias + q * 8 + 4);
        float bb[8] = {a.x,a.y,a.z,a.w,b.x,b.y,b.z,b.w};
#pragma unroll
        for (int i = 0; i < 8; i++) x[i] = fmaxf(fmaf(acc[i], inv, bb[i]), 0.f);
    }

    float s1 = 0.f, s2 = 0.f;
#pragma unroll
    for (int i = 0; i < 8; i++) { s1 += x[i]; s2 += x[i] * x[i]; }
#pragma unroll
    for (int off = 8; off; off >>= 1) {
        s1 += __shfl_xor(s1, off, 64);
        s2 += __shfl_xor(s2, off, 64);
    }
    float mu = s1 * (1.f / 128.f);
    float var = s2 * (1.f / 128.f) - mu * mu;
    float rstd = rsqrtf(var + 1e-5f);

    if (lane < 16) {
        float4 ga = *(const float4*)(g_ln + q * 8);
        float4 gb = *(const float4*)(g_ln + q * 8 + 4);
        float4 ba = *(const float4*)(b_ln + q * 8);
        float4 bb = *(const float4*)(b_ln + q * 8 + 4);
        float o[8];
        o[0] = (x[0]-mu)*rstd*ga.x + ba.x;
        o[1] = (x[1]-mu)*rstd*ga.y + ba.y;
        o[2] = (x[2]-mu)*rstd*ga.z + ba.z;
        o[3] = (x[3]-mu)*rstd*ga.w + ba.w;
        o[4] = (x[4]-mu)*rstd*gb.x + bb.x;
        o[5] = (x[5]-mu)*rstd*gb.y + bb.y;
        o[6] = (x[6]-mu)*rstd*gb.z + bb.z;
        o[7] = (x[7]-mu)*rstd*gb.w + bb.w;
        __half2 p0 = __floats2half2_rn(o[0], o[1]);
        __half2 p1 = __floats2half2_rn(o[2], o[3]);
        __half2 p2 = __floats2half2_rn(o[4], o[5]);
        __half2 p3 = __floats2half2_rn(o[6], o[7]);
        uint4 u;
        u.x = *(unsigned*)&p0; u.y = *(unsigned*)&p1;
        u.z = *(unsigned*)&p2; u.w = *(unsigned*)&p3;
        *(uint4*)(h16b + ((size_t)d << 8) + (q << 4)) = u;
    }
}

// layer2: fused normalize + bias -> h2h (fp16)
__global__ __launch_bounds__(256, 8) void k_gat2(
    const char* __restrict__ xlb, const char* __restrict__ xrb,
    const float* __restrict__ att, const int* __restrict__ rowptr,
    const int* __restrict__ esrc, const float* __restrict__ bias,
    char* __restrict__ h2b)
{
    int d = (int)((blockIdx.x * 256 + threadIdx.x) >> 6);
    int lane = threadIdx.x & 63;
    int q = lane & 15;

    uint4 xrq = *(const uint4*)(xrb + ((size_t)d << 8) + (q << 4));
    uint4 atq = ld_att_h2(att, q);

    float acc[8]; float den;
    gat_core(xlb, esrc, rowptr[d], rowptr[d + 1], lane, xrq, atq, acc, den);

    float inv = 1.f / (den + 1e-16f);
    if (lane < 16) {
        float4 a = *(const float4*)(bias + q * 8);
        float4 b = *(const float4*)(bias + q * 8 + 4);
        float o[8];
        o[0] = fmaf(acc[0], inv, a.x);
        o[1] = fmaf(acc[1], inv, a.y);
        o[2] = fmaf(acc[2], inv, a.z);
        o[3] = fmaf(acc[3], inv, a.w);
        o[4] = fmaf(acc[4], inv, b.x);
        o[5] = fmaf(acc[5], inv, b.y);
        o[6] = fmaf(acc[6], inv, b.z);
        o[7] = fmaf(acc[7], inv, b.w);
        __half2 p0 = __floats2half2_rn(o[0], o[1]);
        __half2 p1 = __floats2half2_rn(o[2], o[3]);
        __half2 p2 = __floats2half2_rn(o[4], o[5]);
        __half2 p3 = __floats2half2_rn(o[6], o[7]);
        uint4 u;
        u.x = *(unsigned*)&p0; u.y = *(unsigned*)&p1;
        u.z = *(unsigned*)&p2; u.w = *(unsigned*)&p3;
        *(uint4*)(h2b + ((size_t)d << 8) + (q << 4)) = u;
    }
}

// ---------------------------------------------------------------------------
// fused mean-pool + linear head: one block per graph (batch is sorted).
// 8 independent row loads in flight per step (latency-chain /8).
// ---------------------------------------------------------------------------
__global__ __launch_bounds__(128) void k_poolin(
    const __half* __restrict__ h2h, const int* __restrict__ batch,
    const float* __restrict__ W, const float* __restrict__ b,
    float* __restrict__ out)
{
    const int g = blockIdx.x;
    const int f = threadIdx.x;

    // node range [lo, lo2) with batch[n] == g
    int lo = 0, hi = NN;
    while (lo < hi) { int m = (lo + hi) >> 1; if (batch[m] < g) lo = m + 1; else hi = m; }
    int lo2 = lo, hi2 = NN;
    while (lo2 < hi2) { int m = (lo2 + hi2) >> 1; if (batch[m] <= g) lo2 = m + 1; else hi2 = m; }

    float s = 0.f;
    const int last = lo2 - 1;
    for (int n = lo; n < lo2; n += 8) {
        float v[8];
#pragma unroll
        for (int j = 0; j < 8; j++) {
            int nn = min(n + j, last);                  // clamped: loads stay unconditional
            v[j] = __half2float(h2h[(size_t)nn * 128 + f]);
        }
#pragma unroll
        for (int j = 0; j < 8; j++)
            s += (n + j < lo2) ? v[j] : 0.f;
    }

    __shared__ float sm[128];
    sm[f] = s;
    __syncthreads();

    if (f < NC) {
        float invc = 1.f / fmaxf((float)(lo2 - lo), 1.f);
        float a = 0.f;
        for (int k = 0; k < HID; k++)
            a = fmaf(sm[k], W[(size_t)k * NC + f], a);
        out[(size_t)g * NC + f] = fmaf(a, invc, b[f]);
    }
}

// ---------------------------------------------------------------------------
extern "C" void kernel_launch(void* const* d_in, const int* in_sizes, int n_in,
                              void* d_out, int out_size, void* d_ws, size_t ws_size,
                              hipStream_t stream)
{
    const float* x     = (const float*)d_in[0];
    const int*   ei    = (const int*)d_in[1];
    const int*   batch = (const int*)d_in[2];
    const float* Wl1   = (const float*)d_in[3];
    const float* Wr1   = (const float*)d_in[4];
    const float* att1  = (const float*)d_in[5];
    const float* b1    = (const float*)d_in[6];
    const float* g_ln  = (const float*)d_in[7];
    const float* b_ln  = (const float*)d_in[8];
    const float* Wl2   = (const float*)d_in[9];
    const float* Wr2   = (const float*)d_in[10];
    const float* att2  = (const float*)d_in[11];
    const float* b2    = (const float*)d_in[12];
    const float* Wlin  = (const float*)d_in[13];
    const float* blin  = (const float*)d_in[14];
    float* out = (float*)d_out;

    char* ws = (char*)d_ws;
    __half* xlh16 = (__half*)ws;                          // 12.8 MB
    char*   xlb   = ws;
    __half* xrh16 = (__half*)(ws + (size_t)NN * 256);     // 12.8 MB
    char*   xrb   = (char*)xrh16;
    __half* h16   = xrh16 + (size_t)NN * 128;             // 12.8 MB
    __half* h2h   = h16 + (size_t)NN * 128;               // 12.8 MB
    char*   h2b   = (char*)h2h;
    int* rowptr   = (int*)(h2h + (size_t)NN * 128);       // NN+1
    int* esrc     = rowptr + NN + 1;                      // NE+NN
    unsigned* pairbuf = (unsigned*)(esrc + NE + NN);      // NB*BCAP = 6.4 MB
    int* cursor   = (int*)(pairbuf + (size_t)NB * BCAP);  // 256
    __half* wpk1  = (__half*)(cursor + 256);              // 64 KB
    __half* wpk2  = wpk1 + 32768;                         // 64 KB

    const int gat_blocks = (NN * 64) / 256;               // exact: 12500

    // 1) W pack (both layers) + zero cursor
    k_wpackz<<<32, 256, 0, stream>>>(Wl1, Wr1, Wl2, Wr2, wpk1, wpk2, cursor);

    // 2) bucket scatter (blocks 0..195) + layer-1 dual GEMM (blocks 196..977)
    k_bscmg<<<SCB + MGB, 256, 0, stream>>>(ei, cursor, pairbuf, x, wpk1,
                                           xlh16, xrh16);

    // 3) per-bucket CSR finalize
    k_bbuild<<<NB, 256, 0, stream>>>(pairbuf, cursor, rowptr, esrc);

    // 4) layer-1 GAT (+ReLU+LN)
    k_gat1<<<gat_blocks, 256, 0, stream>>>(xlb, xrb, att1, rowptr, esrc,
                                           b1, g_ln, b_ln, (char*)h16);

    // 5) layer-2 dual GEMM
    k_mgemm2<<<MGB, 256, 0, stream>>>(h16, wpk2, xlh16, xrh16);

    // 6) layer-2 GAT
    k_gat2<<<gat_blocks, 256, 0, stream>>>(xlb, xrb, att2, rowptr, esrc,
                                           b2, h2b);

    // 7) fused mean-pool + linear head
    k_poolin<<<NG, 128, 0, stream>>>(h2h, batch, Wlin, blin, out);
}